// Round 5
// baseline (243.914 us; speedup 1.0000x reference)
//
#include <hip/hip_runtime.h>
#include <cstdint>
#include <cstddef>

#define CAP 64
#define NSP 119
#define CPAD 16   // padded cnt stride (ints) = 64B/counter

__device__ constexpr int IDX2[9]  = {0,1,2, 1,3,4, 2,4,5};
__device__ constexpr int IDX3[27] = {0,1,2, 1,3,4, 2,4,5,
                                     1,3,4, 3,6,7, 4,7,8,
                                     2,4,5, 4,7,8, 5,8,9};
__device__ constexpr int PR2[15] = {0,1,1,2,2,2,3,3,3,3,4,4,4,4,4};
__device__ constexpr int PS2[15] = {0,0,1,0,1,2,0,1,2,3,0,1,2,3,4};
__device__ constexpr int CB4[15] = {50,51,52,54,55,57,60,61,63,66,70,71,73,76,80};

__global__ __launch_bounds__(256) void rz_pack_kernel(
    const float* __restrict__ R, const int* __restrict__ Z,
    float4* __restrict__ RZ, int n_atoms)
{
    int t = blockIdx.x * blockDim.x + threadIdx.x;
    if (t >= n_atoms) return;
    RZ[t] = make_float4(R[3*t], R[3*t+1], R[3*t+2], __int_as_float(Z[t]));
}

__global__ __launch_bounds__(256) void pad_w_kernel(
    const float* __restrict__ W, float* __restrict__ Wp, int n_el)
{
    int t = blockIdx.x * blockDim.x + threadIdx.x;
    if (t >= n_el) return;
    int rc = t / 36;
    int u  = t - rc * 36;
    Wp[t] = (u < 35) ? W[rc * 35 + u] : 0.f;
}

// ---------- shared per-edge math ----------
__device__ __forceinline__ bool edge_math(
    float4 rzi, float4 rzj, const float4* __restrict__ Wp4,
    float rv[5], float dn[3])
{
    float dx = rzj.x - rzi.x, dy = rzj.y - rzi.y, dz = rzj.z - rzi.z;
    float dr = sqrtf(dx*dx + dy*dy + dz*dz);
    if (!(dr < 6.0f)) return false;

    float inv = 1.0f / (dr + 1e-5f);
    dn[0] = dx*inv; dn[1] = dy*inv; dn[2] = dz*inv;

    const float betta      = 49.0f/36.0f;
    const float rad_norm   = 0.96481270f;
    const float embed_norm = 0.37796447f;
    const float PI_F       = 3.14159265358979f;
    float cut = 0.5f * (__cosf(PI_F * dr * (1.0f/6.0f)) + 1.0f) * rad_norm * embed_norm;

    float basis[7];
    #pragma unroll
    for (int n = 0; n < 7; n++) {
        float d = dr - (0.5f + (5.5f/7.0f) * (float)n);
        basis[n] = __expf(-betta * d * d);
    }

    int zi = __float_as_int(rzi.w);
    int zj = __float_as_int(rzj.w);
    int base4 = (zi * NSP + zj) * 9;

    float rad[5] = {0,0,0,0,0};
    #pragma unroll
    for (int q = 0; q < 9; q++) {
        float4 wq = Wp4[base4 + q];
        #pragma unroll
        for (int c = 0; c < 4; c++) {
            int f = 4*q + c;
            if (f < 35) {
                float wv = (c==0) ? wq.x : (c==1) ? wq.y : (c==2) ? wq.z : wq.w;
                rad[f/7] += basis[f%7] * wv;
            }
        }
    }
    #pragma unroll
    for (int r = 0; r < 5; r++) rv[r] = rad[r] * cut;
    return true;
}

// ---------- primary path: edge-parallel compute + scatter (transposed idx) ----------
__global__ __launch_bounds__(256) void edge_compute_kernel(
    const int* __restrict__ nbr, const float4* __restrict__ RZ,
    const float4* __restrict__ Wp4,
    int* __restrict__ cnt, int* __restrict__ binsIdxT,
    float4* __restrict__ edgeF, int n_edges, int n_atoms)
{
    int e = blockIdx.x * blockDim.x + threadIdx.x;
    if (e >= n_edges) return;
    int i = nbr[e];
    int j = nbr[n_edges + e];
    if (i == j) return;
    float4 rzi = RZ[i];
    float4 rzj = RZ[j];
    float rv[5], dn[3];
    if (!edge_math(rzi, rzj, Wp4, rv, dn)) return;

    int pos = atomicAdd(&cnt[j * CPAD], 1);
    if (pos < CAP) {
        binsIdxT[(size_t)pos * n_atoms + j] = e;     // slot-major: coalesced read later
        edgeF[2*(size_t)e + 0] = make_float4(rv[0], rv[1], rv[2], rv[3]);
        edgeF[2*(size_t)e + 1] = make_float4(rv[4], dn[0], dn[1], dn[2]);
    }
}

// ---------- fallback path: round-3 scatter (idx only, unpadded cnt) ----------
__global__ __launch_bounds__(256) void scatter_bins_kernel(
    const int* __restrict__ nbr, int* __restrict__ cnt,
    int* __restrict__ bins, int n_edges)
{
    int e = blockIdx.x * blockDim.x + threadIdx.x;
    if (e >= n_edges) return;
    int i = nbr[e];
    int j = nbr[n_edges + e];
    if (i == j) return;
    int pos = atomicAdd(&cnt[j], 1);
    if (pos < CAP) bins[(size_t)j * CAP + pos] = i;
}

// ---------- contraction helpers (operands in LDS) ----------
__device__ __forceinline__ void c6_range(const float* m, float* o, int plo, int phi) {
    for (int p = plo; p < phi; p++) {
        int r = PR2[p], s = PS2[p];
        const float* m3r = m + 50 + r * 10;
        const float* m3s = m + 50 + s * 10;
        float A[3][3] = {{0,0,0},{0,0,0},{0,0,0}};
        #pragma unroll
        for (int i = 0; i < 3; i++)
            #pragma unroll
            for (int j = 0; j < 3; j++)
                #pragma unroll
                for (int k = 0; k < 3; k++)
                    #pragma unroll
                    for (int l = 0; l < 3; l++)
                        A[k][l] += m3r[IDX3[(i*3+j)*3+k]] * m3s[IDX3[(i*3+j)*3+l]];
        int col = 160 + p * 5;
        for (int t = 0; t < 5; t++) {
            const float* m2t = m + 20 + t * 6;
            float acc = 0.f;
            #pragma unroll
            for (int k = 0; k < 3; k++)
                #pragma unroll
                for (int l = 0; l < 3; l++)
                    acc += A[k][l] * m2t[IDX2[k*3+l]];
            o[col + t] = acc;
        }
    }
}

__device__ __forceinline__ void c4_range(const float* m, float* o, int plo, int phi) {
    for (int p = plo; p < phi; p++) {
        int r = PR2[p], s = PS2[p];
        const float* m2r = m + 20 + r * 6;
        const float* m2s = m + 20 + s * 6;
        float B[3][3] = {{0,0,0},{0,0,0},{0,0,0}};
        #pragma unroll
        for (int i = 0; i < 3; i++)
            #pragma unroll
            for (int j = 0; j < 3; j++)
                #pragma unroll
                for (int k = 0; k < 3; k++)
                    B[j][k] += m2r[IDX2[i*3+j]] * m2s[IDX2[i*3+k]];
        int col = CB4[p];
        for (int t = 0; t <= s; t++) {
            const float* m2t = m + 20 + t * 6;
            float acc = 0.f;
            #pragma unroll
            for (int j = 0; j < 3; j++)
                #pragma unroll
                for (int k = 0; k < 3; k++)
                    acc += B[j][k] * m2t[IDX2[j*3+k]];
            o[col + t] = acc;
        }
    }
}

__device__ __forceinline__ void c5_range(const float* m, float* o, int plo, int phi) {
    for (int p = plo; p < phi; p++) {
        int r = PR2[p], s = PS2[p];
        const float* m1r = m + 5 + r * 3;
        const float* m1s = m + 5 + s * 3;
        float P[3][3];
        #pragma unroll
        for (int i = 0; i < 3; i++)
            #pragma unroll
            for (int j = 0; j < 3; j++)
                P[i][j] = m1r[i] * m1s[j];
        int col = 85 + p * 5;
        for (int t = 0; t < 5; t++) {
            const float* m2t = m + 20 + t * 6;
            float acc = 0.f;
            #pragma unroll
            for (int i = 0; i < 3; i++)
                #pragma unroll
                for (int j = 0; j < 3; j++)
                    acc += P[i][j] * m2t[IDX2[i*3+j]];
            o[col + t] = acc;
        }
    }
}

__device__ __forceinline__ void c7_all(const float* m, float* o) {
    for (int r = 0; r < 5; r++) {
        const float* m3r = m + 50 + r * 10;
        for (int s = 0; s < 5; s++) {
            const float* m2s = m + 20 + s * 6;
            float v[3] = {0,0,0};
            #pragma unroll
            for (int i = 0; i < 3; i++)
                #pragma unroll
                for (int j = 0; j < 3; j++)
                    #pragma unroll
                    for (int k = 0; k < 3; k++)
                        v[k] += m3r[IDX3[(i*3+j)*3+k]] * m2s[IDX2[i*3+j]];
            int col = 235 + (r * 5 + s) * 5;
            for (int t = 0; t < 5; t++) {
                const float* m1t = m + 5 + t * 3;
                o[col + t] = v[0]*m1t[0] + v[1]*m1t[1] + v[2]*m1t[2];
            }
        }
    }
}

__device__ __forceinline__ void c0123(const float* m, float* o) {
    for (int r = 0; r < 5; r++) o[r] = m[r];
    const float W2[6]  = {1,2,2,1,2,1};
    const float W3[10] = {1,3,3,3,6,3,1,3,3,1};
    int c1 = 5, c2 = 20, c3 = 35;
    for (int r = 0; r < 5; r++) {
        const float* a1r = m + 5 + r * 3;
        const float* a2r = m + 20 + r * 6;
        const float* a3r = m + 50 + r * 10;
        for (int s = 0; s <= r; s++) {
            const float* a1s = m + 5 + s * 3;
            const float* a2s = m + 20 + s * 6;
            const float* a3s = m + 50 + s * 10;
            float d1 = 0.f, d2 = 0.f, d3 = 0.f;
            #pragma unroll
            for (int u = 0; u < 3; u++)  d1 += a1r[u] * a1s[u];
            #pragma unroll
            for (int u = 0; u < 6; u++)  d2 += W2[u] * a2r[u] * a2s[u];
            #pragma unroll
            for (int u = 0; u < 10; u++) d3 += W3[u] * a3r[u] * a3s[u];
            o[c1++] = d1; o[c2++] = d2; o[c3++] = d3;
        }
    }
}

__device__ __forceinline__ void contract_4wave(
    float sm[64][101], int lane, int w, int a0, int n_atoms, float* __restrict__ out)
{
    int aa = a0 + lane;
    if (aa < n_atoms) {
        const float* m = sm[lane];
        float* o = out + (size_t)aa * 360;
        if (w == 0) {
            c6_range(m, o, 0, 10);
        } else if (w == 1) {
            c6_range(m, o, 10, 15);
            c4_range(m, o, 0, 7);
        } else if (w == 2) {
            c4_range(m, o, 7, 15);
            c5_range(m, o, 0, 15);
        } else {
            c7_all(m, o);
            c0123(m, o);
        }
    }
}

// ---------- primary accumulate+contract: lane=atom, wave=k-slice ----------
__global__ __launch_bounds__(256) void accum_contract_kernel(
    const int* __restrict__ cnt, const int* __restrict__ binsIdxT,
    const float4* __restrict__ edgeF,
    float* __restrict__ out, int n_atoms)
{
    __shared__ float sm[64][101];   // stride 101: bank-conflict-free
    int tid  = threadIdx.x;
    int lane = tid & 63;
    int w    = tid >> 6;
    int a0   = blockIdx.x * 64;
    int a    = a0 + lane;

    // zero the staging tile
    float* smf = &sm[0][0];
    for (int t = tid; t < 64*101; t += 256) smf[t] = 0.f;
    __syncthreads();

    float acc[100];
    #pragma unroll
    for (int u = 0; u < 100; u++) acc[u] = 0.f;

    if (a < n_atoms) {
        int cn = cnt[a * CPAD]; if (cn > CAP) cn = CAP;
        // wave w handles edge slots k = w, w+4, ... for ALL 64 atoms (coalesced idx)
        for (int k = w; k < cn; k += 4) {
            int e = binsIdxT[(size_t)k * n_atoms + a];
            float4 q0 = edgeF[2*(size_t)e + 0];
            float4 q1 = edgeF[2*(size_t)e + 1];
            float rv[5]  = {q0.x, q0.y, q0.z, q0.w, q1.x};
            float dn1[3] = {q1.y, q1.z, q1.w};
            float p2[6] = {dn1[0]*dn1[0], dn1[0]*dn1[1], dn1[0]*dn1[2],
                           dn1[1]*dn1[1], dn1[1]*dn1[2], dn1[2]*dn1[2]};
            float p3[10] = {p2[0]*dn1[0], p2[0]*dn1[1], p2[0]*dn1[2],
                            p2[1]*dn1[1], p2[1]*dn1[2], p2[2]*dn1[2],
                            p2[3]*dn1[1], p2[3]*dn1[2], p2[4]*dn1[2],
                            p2[5]*dn1[2]};
            #pragma unroll
            for (int r = 0; r < 5; r++) {
                float rvv = rv[r];
                acc[r] += rvv;
                #pragma unroll
                for (int u = 0; u < 3; u++)  acc[5  + r*3  + u] += rvv * dn1[u];
                #pragma unroll
                for (int u = 0; u < 6; u++)  acc[20 + r*6  + u] += rvv * p2[u];
                #pragma unroll
                for (int u = 0; u < 10; u++) acc[50 + r*10 + u] += rvv * p3[u];
            }
        }
        // merge the 4 wave-partials via LDS float atomics (conflict-free stride)
        #pragma unroll
        for (int u = 0; u < 100; u++) atomicAdd(&sm[lane][u], acc[u]);
    }
    __syncthreads();

    contract_4wave(sm, lane, w, a0, n_atoms, out);
}

// ---------- fallback accumulate+contract: round-3 gather version ----------
__global__ __launch_bounds__(256) void accum_gather_kernel(
    const float4* __restrict__ RZ, const float4* __restrict__ Wp4,
    const int* __restrict__ cnt, const int* __restrict__ bins,
    float* __restrict__ out, int n_atoms)
{
    __shared__ float sm[64][101];
    int tid = threadIdx.x;
    int a0  = blockIdx.x * 64;
    int g   = tid >> 2;
    int l4  = tid & 3;
    int a   = a0 + g;

    float acc[100];
    #pragma unroll
    for (int u = 0; u < 100; u++) acc[u] = 0.f;

    if (a < n_atoms) {
        int cn = cnt[a]; if (cn > CAP) cn = CAP;
        float4 rza = RZ[a];
        for (int e = l4; e < cn; e += 4) {
            int i = bins[(size_t)a * CAP + e];
            float4 rzi = RZ[i];
            float rv[5], dn1[3];
            if (!edge_math(rzi, rza, Wp4, rv, dn1)) continue;
            float p2[6] = {dn1[0]*dn1[0], dn1[0]*dn1[1], dn1[0]*dn1[2],
                           dn1[1]*dn1[1], dn1[1]*dn1[2], dn1[2]*dn1[2]};
            float p3[10] = {p2[0]*dn1[0], p2[0]*dn1[1], p2[0]*dn1[2],
                            p2[1]*dn1[1], p2[1]*dn1[2], p2[2]*dn1[2],
                            p2[3]*dn1[1], p2[3]*dn1[2], p2[4]*dn1[2],
                            p2[5]*dn1[2]};
            #pragma unroll
            for (int r = 0; r < 5; r++) {
                float rvv = rv[r];
                acc[r] += rvv;
                #pragma unroll
                for (int u = 0; u < 3; u++)  acc[5  + r*3  + u] += rvv * dn1[u];
                #pragma unroll
                for (int u = 0; u < 6; u++)  acc[20 + r*6  + u] += rvv * p2[u];
                #pragma unroll
                for (int u = 0; u < 10; u++) acc[50 + r*10 + u] += rvv * p3[u];
            }
        }
    }

    #pragma unroll
    for (int u = 0; u < 100; u++) {
        acc[u] += __shfl_xor(acc[u], 1);
        acc[u] += __shfl_xor(acc[u], 2);
    }
    if (a < n_atoms && l4 == 0) {
        #pragma unroll
        for (int u = 0; u < 100; u++) sm[g][u] = acc[u];
    }
    __syncthreads();

    contract_4wave(sm, tid & 63, tid >> 6, a0, n_atoms, out);
}

extern "C" void kernel_launch(void* const* d_in, const int* in_sizes, int n_in,
                              void* d_out, int out_size, void* d_ws, size_t ws_size,
                              hipStream_t stream)
{
    const float* R   = (const float*)d_in[0];
    const int*   Z   = (const int*)d_in[1];
    const int*   nbr = (const int*)d_in[2];
    const float* W   = (const float*)d_in[4];
    float* out = (float*)d_out;

    int n_atoms = in_sizes[0] / 3;
    int n_edges = in_sizes[2] / 2;
    int n_wel   = NSP * NSP * 36;

    char* ws = (char*)d_ws;

    size_t szCntPad = (size_t)n_atoms * CPAD * 4;
    size_t szIdx    = (size_t)n_atoms * CAP * 4;
    size_t szEdgeF  = (size_t)n_edges * 32;
    size_t szRZ     = (size_t)n_atoms * 16;
    size_t szWp     = (size_t)n_wel * 4;
    size_t needP    = szCntPad + szIdx + szEdgeF + szRZ + szWp;

    if (ws_size >= needP) {
        // primary: payload path, transposed idx bins
        int*    cnt      = (int*)ws;
        int*    binsIdxT = (int*)(ws + szCntPad);
        float4* edgeF    = (float4*)(ws + szCntPad + szIdx);
        float4* RZ       = (float4*)(ws + szCntPad + szIdx + szEdgeF);
        float4* Wp4      = (float4*)(ws + szCntPad + szIdx + szEdgeF + szRZ);

        hipMemsetAsync(cnt, 0, szCntPad, stream);
        rz_pack_kernel<<<(n_atoms + 255)/256, 256, 0, stream>>>(R, Z, RZ, n_atoms);
        pad_w_kernel<<<(n_wel + 255)/256, 256, 0, stream>>>(W, (float*)Wp4, n_wel);
        edge_compute_kernel<<<(n_edges + 255)/256, 256, 0, stream>>>(
            nbr, RZ, Wp4, cnt, binsIdxT, edgeF, n_edges, n_atoms);
        accum_contract_kernel<<<(n_atoms + 63)/64, 256, 0, stream>>>(
            cnt, binsIdxT, edgeF, out, n_atoms);
    } else {
        // fallback: proven round-3 footprint (~15.9 MB)
        int*    cnt  = (int*)ws;
        int*    bins = (int*)(ws + 204800);
        float4* RZ   = (float4*)(ws + 204800 + szIdx);
        float4* Wp4  = (float4*)(ws + 204800 + szIdx + szRZ);

        hipMemsetAsync(cnt, 0, (size_t)n_atoms * 4, stream);
        rz_pack_kernel<<<(n_atoms + 255)/256, 256, 0, stream>>>(R, Z, RZ, n_atoms);
        pad_w_kernel<<<(n_wel + 255)/256, 256, 0, stream>>>(W, (float*)Wp4, n_wel);
        scatter_bins_kernel<<<(n_edges + 255)/256, 256, 0, stream>>>(nbr, cnt, bins, n_edges);
        accum_gather_kernel<<<(n_atoms + 63)/64, 256, 0, stream>>>(
            RZ, Wp4, cnt, bins, out, n_atoms);
    }
}

// Round 6
// 124.000 us; speedup vs baseline: 1.9671x; 1.9671x over previous
//
#include <hip/hip_runtime.h>
#include <cstdint>
#include <cstddef>

#define CAP 64
#define NSP 119
#define CPAD 16   // padded cnt stride (ints) = 64B/counter

__device__ constexpr int IDX2[9]  = {0,1,2, 1,3,4, 2,4,5};
__device__ constexpr int IDX3[27] = {0,1,2, 1,3,4, 2,4,5,
                                     1,3,4, 3,6,7, 4,7,8,
                                     2,4,5, 4,7,8, 5,8,9};
__device__ constexpr int PR2[15] = {0,1,1,2,2,2,3,3,3,3,4,4,4,4,4};
__device__ constexpr int PS2[15] = {0,0,1,0,1,2,0,1,2,3,0,1,2,3,4};
__device__ constexpr int CB4[15] = {50,51,52,54,55,57,60,61,63,66,70,71,73,76,80};

__global__ __launch_bounds__(256) void rz_pack_kernel(
    const float* __restrict__ R, const int* __restrict__ Z,
    float4* __restrict__ RZ, int n_atoms)
{
    int t = blockIdx.x * blockDim.x + threadIdx.x;
    if (t >= n_atoms) return;
    RZ[t] = make_float4(R[3*t], R[3*t+1], R[3*t+2], __int_as_float(Z[t]));
}

__global__ __launch_bounds__(256) void pad_w_kernel(
    const float* __restrict__ W, float* __restrict__ Wp, int n_el)
{
    int t = blockIdx.x * blockDim.x + threadIdx.x;
    if (t >= n_el) return;
    int rc = t / 36;
    int u  = t - rc * 36;
    Wp[t] = (u < 35) ? W[rc * 35 + u] : 0.f;
}

// ---------- shared per-edge math ----------
__device__ __forceinline__ bool edge_math(
    float4 rzi, float4 rzj, const float4* __restrict__ Wp4,
    float rv[5], float dn[3])
{
    float dx = rzj.x - rzi.x, dy = rzj.y - rzi.y, dz = rzj.z - rzi.z;
    float dr = sqrtf(dx*dx + dy*dy + dz*dz);
    if (!(dr < 6.0f)) return false;

    float inv = 1.0f / (dr + 1e-5f);
    dn[0] = dx*inv; dn[1] = dy*inv; dn[2] = dz*inv;

    const float betta      = 49.0f/36.0f;
    const float rad_norm   = 0.96481270f;
    const float embed_norm = 0.37796447f;
    const float PI_F       = 3.14159265358979f;
    float cut = 0.5f * (__cosf(PI_F * dr * (1.0f/6.0f)) + 1.0f) * rad_norm * embed_norm;

    float basis[7];
    #pragma unroll
    for (int n = 0; n < 7; n++) {
        float d = dr - (0.5f + (5.5f/7.0f) * (float)n);
        basis[n] = __expf(-betta * d * d);
    }

    int zi = __float_as_int(rzi.w);
    int zj = __float_as_int(rzj.w);
    int base4 = (zi * NSP + zj) * 9;

    float rad[5] = {0,0,0,0,0};
    #pragma unroll
    for (int q = 0; q < 9; q++) {
        float4 wq = Wp4[base4 + q];
        #pragma unroll
        for (int c = 0; c < 4; c++) {
            int f = 4*q + c;
            if (f < 35) {
                float wv = (c==0) ? wq.x : (c==1) ? wq.y : (c==2) ? wq.z : wq.w;
                rad[f/7] += basis[f%7] * wv;
            }
        }
    }
    #pragma unroll
    for (int r = 0; r < 5; r++) rv[r] = rad[r] * cut;
    return true;
}

// ---------- primary: edge-parallel compute, payload written AT slot ----------
__global__ __launch_bounds__(256) void edge_compute_slot_kernel(
    const int* __restrict__ nbr, const float4* __restrict__ RZ,
    const float4* __restrict__ Wp4,
    int* __restrict__ cnt, float4* __restrict__ pay, int n_edges)
{
    int e = blockIdx.x * blockDim.x + threadIdx.x;
    if (e >= n_edges) return;
    int i = nbr[e];
    int j = nbr[n_edges + e];
    if (i == j) return;
    float4 rzi = RZ[i];
    float4 rzj = RZ[j];
    float rv[5], dn[3];
    if (!edge_math(rzi, rzj, Wp4, rv, dn)) return;

    int pos = atomicAdd(&cnt[j * CPAD], 1);
    if (pos < CAP) {
        size_t slot = ((size_t)j * CAP + pos) * 2;
        pay[slot + 0] = make_float4(rv[0], rv[1], rv[2], rv[3]);
        pay[slot + 1] = make_float4(rv[4], dn[0], dn[1], dn[2]);
    }
}

// ---------- round-4 fallback: edge compute scattered idx + edge-ordered payload ----------
__global__ __launch_bounds__(256) void edge_compute_r4_kernel(
    const int* __restrict__ nbr, const float4* __restrict__ RZ,
    const float4* __restrict__ Wp4,
    int* __restrict__ cnt, int* __restrict__ binsIdx,
    float4* __restrict__ edgeF, int n_edges)
{
    int e = blockIdx.x * blockDim.x + threadIdx.x;
    if (e >= n_edges) return;
    int i = nbr[e];
    int j = nbr[n_edges + e];
    if (i == j) return;
    float4 rzi = RZ[i];
    float4 rzj = RZ[j];
    float rv[5], dn[3];
    if (!edge_math(rzi, rzj, Wp4, rv, dn)) return;

    int pos = atomicAdd(&cnt[j * CPAD], 1);
    if (pos < CAP) {
        binsIdx[(size_t)j * CAP + pos] = e;
        edgeF[2*(size_t)e + 0] = make_float4(rv[0], rv[1], rv[2], rv[3]);
        edgeF[2*(size_t)e + 1] = make_float4(rv[4], dn[0], dn[1], dn[2]);
    }
}

// ---------- round-3 fallback: scatter idx only ----------
__global__ __launch_bounds__(256) void scatter_bins_kernel(
    const int* __restrict__ nbr, int* __restrict__ cnt,
    int* __restrict__ bins, int n_edges)
{
    int e = blockIdx.x * blockDim.x + threadIdx.x;
    if (e >= n_edges) return;
    int i = nbr[e];
    int j = nbr[n_edges + e];
    if (i == j) return;
    int pos = atomicAdd(&cnt[j], 1);
    if (pos < CAP) bins[(size_t)j * CAP + pos] = i;
}

// ---------- contraction helpers (operands in LDS) ----------
__device__ __forceinline__ void c6_range(const float* m, float* o, int plo, int phi) {
    for (int p = plo; p < phi; p++) {
        int r = PR2[p], s = PS2[p];
        const float* m3r = m + 50 + r * 10;
        const float* m3s = m + 50 + s * 10;
        float A[3][3] = {{0,0,0},{0,0,0},{0,0,0}};
        #pragma unroll
        for (int i = 0; i < 3; i++)
            #pragma unroll
            for (int j = 0; j < 3; j++)
                #pragma unroll
                for (int k = 0; k < 3; k++)
                    #pragma unroll
                    for (int l = 0; l < 3; l++)
                        A[k][l] += m3r[IDX3[(i*3+j)*3+k]] * m3s[IDX3[(i*3+j)*3+l]];
        int col = 160 + p * 5;
        for (int t = 0; t < 5; t++) {
            const float* m2t = m + 20 + t * 6;
            float acc = 0.f;
            #pragma unroll
            for (int k = 0; k < 3; k++)
                #pragma unroll
                for (int l = 0; l < 3; l++)
                    acc += A[k][l] * m2t[IDX2[k*3+l]];
            o[col + t] = acc;
        }
    }
}

__device__ __forceinline__ void c4_range(const float* m, float* o, int plo, int phi) {
    for (int p = plo; p < phi; p++) {
        int r = PR2[p], s = PS2[p];
        const float* m2r = m + 20 + r * 6;
        const float* m2s = m + 20 + s * 6;
        float B[3][3] = {{0,0,0},{0,0,0},{0,0,0}};
        #pragma unroll
        for (int i = 0; i < 3; i++)
            #pragma unroll
            for (int j = 0; j < 3; j++)
                #pragma unroll
                for (int k = 0; k < 3; k++)
                    B[j][k] += m2r[IDX2[i*3+j]] * m2s[IDX2[i*3+k]];
        int col = CB4[p];
        for (int t = 0; t <= s; t++) {
            const float* m2t = m + 20 + t * 6;
            float acc = 0.f;
            #pragma unroll
            for (int j = 0; j < 3; j++)
                #pragma unroll
                for (int k = 0; k < 3; k++)
                    acc += B[j][k] * m2t[IDX2[j*3+k]];
            o[col + t] = acc;
        }
    }
}

__device__ __forceinline__ void c5_range(const float* m, float* o, int plo, int phi) {
    for (int p = plo; p < phi; p++) {
        int r = PR2[p], s = PS2[p];
        const float* m1r = m + 5 + r * 3;
        const float* m1s = m + 5 + s * 3;
        float P[3][3];
        #pragma unroll
        for (int i = 0; i < 3; i++)
            #pragma unroll
            for (int j = 0; j < 3; j++)
                P[i][j] = m1r[i] * m1s[j];
        int col = 85 + p * 5;
        for (int t = 0; t < 5; t++) {
            const float* m2t = m + 20 + t * 6;
            float acc = 0.f;
            #pragma unroll
            for (int i = 0; i < 3; i++)
                #pragma unroll
                for (int j = 0; j < 3; j++)
                    acc += P[i][j] * m2t[IDX2[i*3+j]];
            o[col + t] = acc;
        }
    }
}

__device__ __forceinline__ void c7_all(const float* m, float* o) {
    for (int r = 0; r < 5; r++) {
        const float* m3r = m + 50 + r * 10;
        for (int s = 0; s < 5; s++) {
            const float* m2s = m + 20 + s * 6;
            float v[3] = {0,0,0};
            #pragma unroll
            for (int i = 0; i < 3; i++)
                #pragma unroll
                for (int j = 0; j < 3; j++)
                    #pragma unroll
                    for (int k = 0; k < 3; k++)
                        v[k] += m3r[IDX3[(i*3+j)*3+k]] * m2s[IDX2[i*3+j]];
            int col = 235 + (r * 5 + s) * 5;
            for (int t = 0; t < 5; t++) {
                const float* m1t = m + 5 + t * 3;
                o[col + t] = v[0]*m1t[0] + v[1]*m1t[1] + v[2]*m1t[2];
            }
        }
    }
}

__device__ __forceinline__ void c0123(const float* m, float* o) {
    for (int r = 0; r < 5; r++) o[r] = m[r];
    const float W2[6]  = {1,2,2,1,2,1};
    const float W3[10] = {1,3,3,3,6,3,1,3,3,1};
    int c1 = 5, c2 = 20, c3 = 35;
    for (int r = 0; r < 5; r++) {
        const float* a1r = m + 5 + r * 3;
        const float* a2r = m + 20 + r * 6;
        const float* a3r = m + 50 + r * 10;
        for (int s = 0; s <= r; s++) {
            const float* a1s = m + 5 + s * 3;
            const float* a2s = m + 20 + s * 6;
            const float* a3s = m + 50 + s * 10;
            float d1 = 0.f, d2 = 0.f, d3 = 0.f;
            #pragma unroll
            for (int u = 0; u < 3; u++)  d1 += a1r[u] * a1s[u];
            #pragma unroll
            for (int u = 0; u < 6; u++)  d2 += W2[u] * a2r[u] * a2s[u];
            #pragma unroll
            for (int u = 0; u < 10; u++) d3 += W3[u] * a3r[u] * a3s[u];
            o[c1++] = d1; o[c2++] = d2; o[c3++] = d3;
        }
    }
}

__device__ __forceinline__ void contract_4wave(
    float sm[64][101], int lane, int w, int a0, int n_atoms, float* __restrict__ out)
{
    int aa = a0 + lane;
    if (aa < n_atoms) {
        const float* m = sm[lane];
        float* o = out + (size_t)aa * 360;
        if (w == 0) {
            c6_range(m, o, 0, 10);
        } else if (w == 1) {
            c6_range(m, o, 10, 15);
            c4_range(m, o, 0, 7);
        } else if (w == 2) {
            c4_range(m, o, 7, 15);
            c5_range(m, o, 0, 15);
        } else {
            c7_all(m, o);
            c0123(m, o);
        }
    }
}

__device__ __forceinline__ void moments_to_out(
    float acc[100], float sm[64][101], int tid, int a0, int n_atoms,
    float* __restrict__ out)
{
    #pragma unroll
    for (int u = 0; u < 100; u++) {
        acc[u] += __shfl_xor(acc[u], 1);
        acc[u] += __shfl_xor(acc[u], 2);
    }
    int g  = tid >> 2;
    int l4 = tid & 3;
    if (a0 + g < n_atoms && l4 == 0) {
        #pragma unroll
        for (int u = 0; u < 100; u++) sm[g][u] = acc[u];
    }
    __syncthreads();
    contract_4wave(sm, tid & 63, tid >> 6, a0, n_atoms, out);
}

// accumulate the 100-moment update for one edge payload
__device__ __forceinline__ void accum_edge(float acc[100], float4 q0, float4 q1)
{
    float rv[5]  = {q0.x, q0.y, q0.z, q0.w, q1.x};
    float dn1[3] = {q1.y, q1.z, q1.w};
    float p2[6] = {dn1[0]*dn1[0], dn1[0]*dn1[1], dn1[0]*dn1[2],
                   dn1[1]*dn1[1], dn1[1]*dn1[2], dn1[2]*dn1[2]};
    float p3[10] = {p2[0]*dn1[0], p2[0]*dn1[1], p2[0]*dn1[2],
                    p2[1]*dn1[1], p2[1]*dn1[2], p2[2]*dn1[2],
                    p2[3]*dn1[1], p2[3]*dn1[2], p2[4]*dn1[2],
                    p2[5]*dn1[2]};
    #pragma unroll
    for (int r = 0; r < 5; r++) {
        float rvv = rv[r];
        acc[r] += rvv;
        #pragma unroll
        for (int u = 0; u < 3; u++)  acc[5  + r*3  + u] += rvv * dn1[u];
        #pragma unroll
        for (int u = 0; u < 6; u++)  acc[20 + r*6  + u] += rvv * p2[u];
        #pragma unroll
        for (int u = 0; u < 10; u++) acc[50 + r*10 + u] += rvv * p3[u];
    }
}

// ---------- primary accumulate+contract: coalesced slot payload ----------
__global__ __launch_bounds__(256) void accum_slot_kernel(
    const int* __restrict__ cnt, const float4* __restrict__ pay,
    float* __restrict__ out, int n_atoms)
{
    __shared__ float sm[64][101];
    int tid = threadIdx.x;
    int a0  = blockIdx.x * 64;
    int g   = tid >> 2;
    int l4  = tid & 3;
    int a   = a0 + g;

    float acc[100];
    #pragma unroll
    for (int u = 0; u < 100; u++) acc[u] = 0.f;

    if (a < n_atoms) {
        int cn = cnt[a * CPAD]; if (cn > CAP) cn = CAP;
        const float4* row = pay + (size_t)a * CAP * 2;
        // 4-lane group reads consecutive 32B slots -> full 128B lines
        for (int es = l4; es < cn; es += 4) {
            float4 q0 = row[2*es + 0];
            float4 q1 = row[2*es + 1];
            accum_edge(acc, q0, q1);
        }
    }
    moments_to_out(acc, sm, tid, a0, n_atoms, out);
}

// ---------- round-4 fallback accumulate ----------
__global__ __launch_bounds__(256) void accum_payload_r4_kernel(
    const int* __restrict__ cnt, const int* __restrict__ binsIdx,
    const float4* __restrict__ edgeF,
    float* __restrict__ out, int n_atoms)
{
    __shared__ float sm[64][101];
    int tid = threadIdx.x;
    int a0  = blockIdx.x * 64;
    int g   = tid >> 2;
    int l4  = tid & 3;
    int a   = a0 + g;

    float acc[100];
    #pragma unroll
    for (int u = 0; u < 100; u++) acc[u] = 0.f;

    if (a < n_atoms) {
        int cn = cnt[a * CPAD]; if (cn > CAP) cn = CAP;
        const int* row = binsIdx + (size_t)a * CAP;
        for (int es = l4; es < cn; es += 4) {
            int e = row[es];
            float4 q0 = edgeF[2*(size_t)e + 0];
            float4 q1 = edgeF[2*(size_t)e + 1];
            accum_edge(acc, q0, q1);
        }
    }
    moments_to_out(acc, sm, tid, a0, n_atoms, out);
}

// ---------- round-3 fallback accumulate (gather + recompute) ----------
__global__ __launch_bounds__(256) void accum_gather_kernel(
    const float4* __restrict__ RZ, const float4* __restrict__ Wp4,
    const int* __restrict__ cnt, const int* __restrict__ bins,
    float* __restrict__ out, int n_atoms)
{
    __shared__ float sm[64][101];
    int tid = threadIdx.x;
    int a0  = blockIdx.x * 64;
    int g   = tid >> 2;
    int l4  = tid & 3;
    int a   = a0 + g;

    float acc[100];
    #pragma unroll
    for (int u = 0; u < 100; u++) acc[u] = 0.f;

    if (a < n_atoms) {
        int cn = cnt[a]; if (cn > CAP) cn = CAP;
        float4 rza = RZ[a];
        for (int e = l4; e < cn; e += 4) {
            int i = bins[(size_t)a * CAP + e];
            float4 rzi = RZ[i];
            float rv[5], dn1[3];
            if (!edge_math(rzi, rza, Wp4, rv, dn1)) continue;
            float4 q0 = make_float4(rv[0], rv[1], rv[2], rv[3]);
            float4 q1 = make_float4(rv[4], dn1[0], dn1[1], dn1[2]);
            accum_edge(acc, q0, q1);
        }
    }
    moments_to_out(acc, sm, tid, a0, n_atoms, out);
}

extern "C" void kernel_launch(void* const* d_in, const int* in_sizes, int n_in,
                              void* d_out, int out_size, void* d_ws, size_t ws_size,
                              hipStream_t stream)
{
    const float* R   = (const float*)d_in[0];
    const int*   Z   = (const int*)d_in[1];
    const int*   nbr = (const int*)d_in[2];
    const float* W   = (const float*)d_in[4];
    float* out = (float*)d_out;

    int n_atoms = in_sizes[0] / 3;
    int n_edges = in_sizes[2] / 2;
    int n_wel   = NSP * NSP * 36;

    char* ws = (char*)d_ws;

    size_t szCntPad = (size_t)n_atoms * CPAD * 4;
    size_t szRZ     = (size_t)n_atoms * 16;
    size_t szWp     = (size_t)n_wel * 4;
    size_t szPay    = (size_t)n_atoms * CAP * 32;       // 32B per slot
    size_t szIdx    = (size_t)n_atoms * CAP * 4;
    size_t szEdgeF  = (size_t)n_edges * 32;

    size_t needSlot = szCntPad + szPay + szRZ + szWp;               // ~108.4 MB
    size_t needR4   = szCntPad + szIdx + szEdgeF + szRZ + szWp;     // ~51 MB
    size_t needR3   = 204800 + szIdx + szRZ + szWp;                 // ~16 MB

    if (ws_size >= needSlot) {
        int*    cnt = (int*)ws;
        float4* pay = (float4*)(ws + szCntPad);
        float4* RZ  = (float4*)(ws + szCntPad + szPay);
        float4* Wp4 = (float4*)(ws + szCntPad + szPay + szRZ);

        hipMemsetAsync(cnt, 0, szCntPad, stream);
        rz_pack_kernel<<<(n_atoms + 255)/256, 256, 0, stream>>>(R, Z, RZ, n_atoms);
        pad_w_kernel<<<(n_wel + 255)/256, 256, 0, stream>>>(W, (float*)Wp4, n_wel);
        edge_compute_slot_kernel<<<(n_edges + 255)/256, 256, 0, stream>>>(
            nbr, RZ, Wp4, cnt, pay, n_edges);
        accum_slot_kernel<<<(n_atoms + 63)/64, 256, 0, stream>>>(
            cnt, pay, out, n_atoms);
    } else if (ws_size >= needR4) {
        int*    cnt     = (int*)ws;
        int*    binsIdx = (int*)(ws + szCntPad);
        float4* edgeF   = (float4*)(ws + szCntPad + szIdx);
        float4* RZ      = (float4*)(ws + szCntPad + szIdx + szEdgeF);
        float4* Wp4     = (float4*)(ws + szCntPad + szIdx + szEdgeF + szRZ);

        hipMemsetAsync(cnt, 0, szCntPad, stream);
        rz_pack_kernel<<<(n_atoms + 255)/256, 256, 0, stream>>>(R, Z, RZ, n_atoms);
        pad_w_kernel<<<(n_wel + 255)/256, 256, 0, stream>>>(W, (float*)Wp4, n_wel);
        edge_compute_r4_kernel<<<(n_edges + 255)/256, 256, 0, stream>>>(
            nbr, RZ, Wp4, cnt, binsIdx, edgeF, n_edges);
        accum_payload_r4_kernel<<<(n_atoms + 63)/64, 256, 0, stream>>>(
            cnt, binsIdx, edgeF, out, n_atoms);
    } else {
        int*    cnt  = (int*)ws;
        int*    bins = (int*)(ws + 204800);
        float4* RZ   = (float4*)(ws + 204800 + szIdx);
        float4* Wp4  = (float4*)(ws + 204800 + szIdx + szRZ);

        hipMemsetAsync(cnt, 0, (size_t)n_atoms * 4, stream);
        rz_pack_kernel<<<(n_atoms + 255)/256, 256, 0, stream>>>(R, Z, RZ, n_atoms);
        pad_w_kernel<<<(n_wel + 255)/256, 256, 0, stream>>>(W, (float*)Wp4, n_wel);
        scatter_bins_kernel<<<(n_edges + 255)/256, 256, 0, stream>>>(nbr, cnt, bins, n_edges);
        accum_gather_kernel<<<(n_atoms + 63)/64, 256, 0, stream>>>(
            RZ, Wp4, cnt, bins, out, n_atoms);
    }
}

// Round 7
// 122.766 us; speedup vs baseline: 1.9868x; 1.0100x over previous
//
#include <hip/hip_runtime.h>
#include <cstdint>
#include <cstddef>

#define CAP 64
#define NSP 119
#define CPAD 16   // padded cnt stride (ints) = 64B/counter

__device__ constexpr int IDX2[9]  = {0,1,2, 1,3,4, 2,4,5};
__device__ constexpr int IDX3[27] = {0,1,2, 1,3,4, 2,4,5,
                                     1,3,4, 3,6,7, 4,7,8,
                                     2,4,5, 4,7,8, 5,8,9};
__device__ constexpr int PR2[15] = {0,1,1,2,2,2,3,3,3,3,4,4,4,4,4};
__device__ constexpr int PS2[15] = {0,0,1,0,1,2,0,1,2,3,0,1,2,3,4};
__device__ constexpr int CB4[15] = {50,51,52,54,55,57,60,61,63,66,70,71,73,76,80};

__global__ __launch_bounds__(256) void rz_pack_kernel(
    const float* __restrict__ R, const int* __restrict__ Z,
    float4* __restrict__ RZ, int n_atoms)
{
    int t = blockIdx.x * blockDim.x + threadIdx.x;
    if (t >= n_atoms) return;
    RZ[t] = make_float4(R[3*t], R[3*t+1], R[3*t+2], __int_as_float(Z[t]));
}

__global__ __launch_bounds__(256) void pad_w_kernel(
    const float* __restrict__ W, float* __restrict__ Wp, int n_el)
{
    int t = blockIdx.x * blockDim.x + threadIdx.x;
    if (t >= n_el) return;
    int rc = t / 36;
    int u  = t - rc * 36;
    Wp[t] = (u < 35) ? W[rc * 35 + u] : 0.f;
}

// ---------- primary: LIGHT edge scatter — 16B payload {dx,dy,dz,Zi} ----------
__global__ __launch_bounds__(256) void edge_light_kernel(
    const int* __restrict__ nbr, const float4* __restrict__ RZ,
    int* __restrict__ cnt, float4* __restrict__ pay, int n_edges)
{
    int e = blockIdx.x * blockDim.x + threadIdx.x;
    if (e >= n_edges) return;
    int i = nbr[e];
    int j = nbr[n_edges + e];
    if (i == j) return;
    float4 rzi = RZ[i];
    float4 rzj = RZ[j];
    float dx = rzj.x - rzi.x, dy = rzj.y - rzi.y, dz = rzj.z - rzi.z;
    float dr2 = dx*dx + dy*dy + dz*dz;
    if (!(dr2 < 36.0f)) return;          // cutoff == 0 outside R_MAX

    int pos = atomicAdd(&cnt[j * CPAD], 1);
    if (pos < CAP) {
        pay[(size_t)j * CAP + pos] = make_float4(dx, dy, dz, rzi.w); // rzi.w = Zi bits
    }
}

// ---------- round-3 fallback: scatter idx only ----------
__global__ __launch_bounds__(256) void scatter_bins_kernel(
    const int* __restrict__ nbr, int* __restrict__ cnt,
    int* __restrict__ bins, int n_edges)
{
    int e = blockIdx.x * blockDim.x + threadIdx.x;
    if (e >= n_edges) return;
    int i = nbr[e];
    int j = nbr[n_edges + e];
    if (i == j) return;
    int pos = atomicAdd(&cnt[j], 1);
    if (pos < CAP) bins[(size_t)j * CAP + pos] = i;
}

// ---------- per-edge math from raw displacement ----------
__device__ __forceinline__ void edge_math_raw(
    float dx, float dy, float dz, int zi, int za,
    const float4* __restrict__ Wp4, float rv[5], float dn[3])
{
    float dr = sqrtf(dx*dx + dy*dy + dz*dz);
    float inv = 1.0f / (dr + 1e-5f);
    dn[0] = dx*inv; dn[1] = dy*inv; dn[2] = dz*inv;

    const float betta      = 49.0f/36.0f;
    const float rad_norm   = 0.96481270f;
    const float embed_norm = 0.37796447f;
    const float PI_F       = 3.14159265358979f;
    float cut = 0.5f * (__cosf(PI_F * dr * (1.0f/6.0f)) + 1.0f) * rad_norm * embed_norm;

    float basis[7];
    #pragma unroll
    for (int n = 0; n < 7; n++) {
        float d = dr - (0.5f + (5.5f/7.0f) * (float)n);
        basis[n] = __expf(-betta * d * d);
    }

    int base4 = (zi * NSP + za) * 9;
    float rad[5] = {0,0,0,0,0};
    #pragma unroll
    for (int q = 0; q < 9; q++) {
        float4 wq = Wp4[base4 + q];
        #pragma unroll
        for (int c = 0; c < 4; c++) {
            int f = 4*q + c;
            if (f < 35) {
                float wv = (c==0) ? wq.x : (c==1) ? wq.y : (c==2) ? wq.z : wq.w;
                rad[f/7] += basis[f%7] * wv;
            }
        }
    }
    #pragma unroll
    for (int r = 0; r < 5; r++) rv[r] = rad[r] * cut;
}

// ---------- contraction helpers (operands in LDS) ----------
__device__ __forceinline__ void c6_range(const float* m, float* o, int plo, int phi) {
    for (int p = plo; p < phi; p++) {
        int r = PR2[p], s = PS2[p];
        const float* m3r = m + 50 + r * 10;
        const float* m3s = m + 50 + s * 10;
        float A[3][3] = {{0,0,0},{0,0,0},{0,0,0}};
        #pragma unroll
        for (int i = 0; i < 3; i++)
            #pragma unroll
            for (int j = 0; j < 3; j++)
                #pragma unroll
                for (int k = 0; k < 3; k++)
                    #pragma unroll
                    for (int l = 0; l < 3; l++)
                        A[k][l] += m3r[IDX3[(i*3+j)*3+k]] * m3s[IDX3[(i*3+j)*3+l]];
        int col = 160 + p * 5;
        for (int t = 0; t < 5; t++) {
            const float* m2t = m + 20 + t * 6;
            float acc = 0.f;
            #pragma unroll
            for (int k = 0; k < 3; k++)
                #pragma unroll
                for (int l = 0; l < 3; l++)
                    acc += A[k][l] * m2t[IDX2[k*3+l]];
            o[col + t] = acc;
        }
    }
}

__device__ __forceinline__ void c4_range(const float* m, float* o, int plo, int phi) {
    for (int p = plo; p < phi; p++) {
        int r = PR2[p], s = PS2[p];
        const float* m2r = m + 20 + r * 6;
        const float* m2s = m + 20 + s * 6;
        float B[3][3] = {{0,0,0},{0,0,0},{0,0,0}};
        #pragma unroll
        for (int i = 0; i < 3; i++)
            #pragma unroll
            for (int j = 0; j < 3; j++)
                #pragma unroll
                for (int k = 0; k < 3; k++)
                    B[j][k] += m2r[IDX2[i*3+j]] * m2s[IDX2[i*3+k]];
        int col = CB4[p];
        for (int t = 0; t <= s; t++) {
            const float* m2t = m + 20 + t * 6;
            float acc = 0.f;
            #pragma unroll
            for (int j = 0; j < 3; j++)
                #pragma unroll
                for (int k = 0; k < 3; k++)
                    acc += B[j][k] * m2t[IDX2[j*3+k]];
            o[col + t] = acc;
        }
    }
}

__device__ __forceinline__ void c5_range(const float* m, float* o, int plo, int phi) {
    for (int p = plo; p < phi; p++) {
        int r = PR2[p], s = PS2[p];
        const float* m1r = m + 5 + r * 3;
        const float* m1s = m + 5 + s * 3;
        float P[3][3];
        #pragma unroll
        for (int i = 0; i < 3; i++)
            #pragma unroll
            for (int j = 0; j < 3; j++)
                P[i][j] = m1r[i] * m1s[j];
        int col = 85 + p * 5;
        for (int t = 0; t < 5; t++) {
            const float* m2t = m + 20 + t * 6;
            float acc = 0.f;
            #pragma unroll
            for (int i = 0; i < 3; i++)
                #pragma unroll
                for (int j = 0; j < 3; j++)
                    acc += P[i][j] * m2t[IDX2[i*3+j]];
            o[col + t] = acc;
        }
    }
}

__device__ __forceinline__ void c7_all(const float* m, float* o) {
    for (int r = 0; r < 5; r++) {
        const float* m3r = m + 50 + r * 10;
        for (int s = 0; s < 5; s++) {
            const float* m2s = m + 20 + s * 6;
            float v[3] = {0,0,0};
            #pragma unroll
            for (int i = 0; i < 3; i++)
                #pragma unroll
                for (int j = 0; j < 3; j++)
                    #pragma unroll
                    for (int k = 0; k < 3; k++)
                        v[k] += m3r[IDX3[(i*3+j)*3+k]] * m2s[IDX2[i*3+j]];
            int col = 235 + (r * 5 + s) * 5;
            for (int t = 0; t < 5; t++) {
                const float* m1t = m + 5 + t * 3;
                o[col + t] = v[0]*m1t[0] + v[1]*m1t[1] + v[2]*m1t[2];
            }
        }
    }
}

__device__ __forceinline__ void c0123(const float* m, float* o) {
    for (int r = 0; r < 5; r++) o[r] = m[r];
    const float W2[6]  = {1,2,2,1,2,1};
    const float W3[10] = {1,3,3,3,6,3,1,3,3,1};
    int c1 = 5, c2 = 20, c3 = 35;
    for (int r = 0; r < 5; r++) {
        const float* a1r = m + 5 + r * 3;
        const float* a2r = m + 20 + r * 6;
        const float* a3r = m + 50 + r * 10;
        for (int s = 0; s <= r; s++) {
            const float* a1s = m + 5 + s * 3;
            const float* a2s = m + 20 + s * 6;
            const float* a3s = m + 50 + s * 10;
            float d1 = 0.f, d2 = 0.f, d3 = 0.f;
            #pragma unroll
            for (int u = 0; u < 3; u++)  d1 += a1r[u] * a1s[u];
            #pragma unroll
            for (int u = 0; u < 6; u++)  d2 += W2[u] * a2r[u] * a2s[u];
            #pragma unroll
            for (int u = 0; u < 10; u++) d3 += W3[u] * a3r[u] * a3s[u];
            o[c1++] = d1; o[c2++] = d2; o[c3++] = d3;
        }
    }
}

__device__ __forceinline__ void contract_4wave(
    float sm[64][101], int lane, int w, int a0, int n_atoms, float* __restrict__ out)
{
    int aa = a0 + lane;
    if (aa < n_atoms) {
        const float* m = sm[lane];
        float* o = out + (size_t)aa * 360;
        if (w == 0) {
            c6_range(m, o, 0, 10);
        } else if (w == 1) {
            c6_range(m, o, 10, 15);
            c4_range(m, o, 0, 7);
        } else if (w == 2) {
            c4_range(m, o, 7, 15);
            c5_range(m, o, 0, 15);
        } else {
            c7_all(m, o);
            c0123(m, o);
        }
    }
}

__device__ __forceinline__ void moments_to_out(
    float acc[100], float sm[64][101], int tid, int a0, int n_atoms,
    float* __restrict__ out)
{
    #pragma unroll
    for (int u = 0; u < 100; u++) {
        acc[u] += __shfl_xor(acc[u], 1);
        acc[u] += __shfl_xor(acc[u], 2);
    }
    int g  = tid >> 2;
    int l4 = tid & 3;
    if (a0 + g < n_atoms && l4 == 0) {
        #pragma unroll
        for (int u = 0; u < 100; u++) sm[g][u] = acc[u];
    }
    __syncthreads();
    contract_4wave(sm, tid & 63, tid >> 6, a0, n_atoms, out);
}

// accumulate the 100-moment update for one edge
__device__ __forceinline__ void accum_edge(float acc[100], const float rv[5], const float dn1[3])
{
    float p2[6] = {dn1[0]*dn1[0], dn1[0]*dn1[1], dn1[0]*dn1[2],
                   dn1[1]*dn1[1], dn1[1]*dn1[2], dn1[2]*dn1[2]};
    float p3[10] = {p2[0]*dn1[0], p2[0]*dn1[1], p2[0]*dn1[2],
                    p2[1]*dn1[1], p2[1]*dn1[2], p2[2]*dn1[2],
                    p2[3]*dn1[1], p2[3]*dn1[2], p2[4]*dn1[2],
                    p2[5]*dn1[2]};
    #pragma unroll
    for (int r = 0; r < 5; r++) {
        float rvv = rv[r];
        acc[r] += rvv;
        #pragma unroll
        for (int u = 0; u < 3; u++)  acc[5  + r*3  + u] += rvv * dn1[u];
        #pragma unroll
        for (int u = 0; u < 6; u++)  acc[20 + r*6  + u] += rvv * p2[u];
        #pragma unroll
        for (int u = 0; u < 10; u++) acc[50 + r*10 + u] += rvv * p3[u];
    }
}

// ---------- primary accumulate+contract: coalesced 16B payload + recompute ----------
__global__ __launch_bounds__(256) void accum_recompute_kernel(
    const int* __restrict__ Z,
    const int* __restrict__ cnt, const float4* __restrict__ pay,
    const float4* __restrict__ Wp4,
    float* __restrict__ out, int n_atoms)
{
    __shared__ float sm[64][101];
    int tid = threadIdx.x;
    int a0  = blockIdx.x * 64;
    int g   = tid >> 2;
    int l4  = tid & 3;
    int a   = a0 + g;

    float acc[100];
    #pragma unroll
    for (int u = 0; u < 100; u++) acc[u] = 0.f;

    if (a < n_atoms) {
        int cn = cnt[a * CPAD]; if (cn > CAP) cn = CAP;
        int za = Z[a];
        const float4* row = pay + (size_t)a * CAP;
        for (int es = l4; es < cn; es += 4) {
            float4 q = row[es];
            int zi = __float_as_int(q.w);
            float rv[5], dn1[3];
            edge_math_raw(q.x, q.y, q.z, zi, za, Wp4, rv, dn1);
            accum_edge(acc, rv, dn1);
        }
    }
    moments_to_out(acc, sm, tid, a0, n_atoms, out);
}

// ---------- round-3 fallback accumulate (gather + recompute) ----------
__global__ __launch_bounds__(256) void accum_gather_kernel(
    const float4* __restrict__ RZ, const float4* __restrict__ Wp4,
    const int* __restrict__ cnt, const int* __restrict__ bins,
    float* __restrict__ out, int n_atoms)
{
    __shared__ float sm[64][101];
    int tid = threadIdx.x;
    int a0  = blockIdx.x * 64;
    int g   = tid >> 2;
    int l4  = tid & 3;
    int a   = a0 + g;

    float acc[100];
    #pragma unroll
    for (int u = 0; u < 100; u++) acc[u] = 0.f;

    if (a < n_atoms) {
        int cn = cnt[a]; if (cn > CAP) cn = CAP;
        float4 rza = RZ[a];
        int za = __float_as_int(rza.w);
        for (int e = l4; e < cn; e += 4) {
            int i = bins[(size_t)a * CAP + e];
            float4 rzi = RZ[i];
            float dx = rza.x - rzi.x, dy = rza.y - rzi.y, dz = rza.z - rzi.z;
            float dr2 = dx*dx + dy*dy + dz*dz;
            if (!(dr2 < 36.0f)) continue;
            int zi = __float_as_int(rzi.w);
            float rv[5], dn1[3];
            edge_math_raw(dx, dy, dz, zi, za, Wp4, rv, dn1);
            accum_edge(acc, rv, dn1);
        }
    }
    moments_to_out(acc, sm, tid, a0, n_atoms, out);
}

extern "C" void kernel_launch(void* const* d_in, const int* in_sizes, int n_in,
                              void* d_out, int out_size, void* d_ws, size_t ws_size,
                              hipStream_t stream)
{
    const float* R   = (const float*)d_in[0];
    const int*   Z   = (const int*)d_in[1];
    const int*   nbr = (const int*)d_in[2];
    const float* W   = (const float*)d_in[4];
    float* out = (float*)d_out;

    int n_atoms = in_sizes[0] / 3;
    int n_edges = in_sizes[2] / 2;
    int n_wel   = NSP * NSP * 36;

    char* ws = (char*)d_ws;

    size_t szCntPad = (size_t)n_atoms * CPAD * 4;       // 3.2 MB
    size_t szRZ     = (size_t)n_atoms * 16;             // 0.8 MB
    size_t szWp     = (size_t)n_wel * 4;                // 2.0 MB
    size_t szPay16  = (size_t)n_atoms * CAP * 16;       // 51.2 MB
    size_t szIdx    = (size_t)n_atoms * CAP * 4;        // 12.8 MB

    size_t needLight = szCntPad + szPay16 + szRZ + szWp;   // ~57 MB

    if (ws_size >= needLight) {
        int*    cnt = (int*)ws;
        float4* pay = (float4*)(ws + szCntPad);
        float4* RZ  = (float4*)(ws + szCntPad + szPay16);
        float4* Wp4 = (float4*)(ws + szCntPad + szPay16 + szRZ);

        hipMemsetAsync(cnt, 0, szCntPad, stream);
        rz_pack_kernel<<<(n_atoms + 255)/256, 256, 0, stream>>>(R, Z, RZ, n_atoms);
        pad_w_kernel<<<(n_wel + 255)/256, 256, 0, stream>>>(W, (float*)Wp4, n_wel);
        edge_light_kernel<<<(n_edges + 255)/256, 256, 0, stream>>>(
            nbr, RZ, cnt, pay, n_edges);
        accum_recompute_kernel<<<(n_atoms + 63)/64, 256, 0, stream>>>(
            Z, cnt, pay, Wp4, out, n_atoms);
    } else {
        // fallback: round-3 footprint (~16 MB)
        int*    cnt  = (int*)ws;
        int*    bins = (int*)(ws + 204800);
        float4* RZ   = (float4*)(ws + 204800 + szIdx);
        float4* Wp4  = (float4*)(ws + 204800 + szIdx + szRZ);

        hipMemsetAsync(cnt, 0, (size_t)n_atoms * 4, stream);
        rz_pack_kernel<<<(n_atoms + 255)/256, 256, 0, stream>>>(R, Z, RZ, n_atoms);
        pad_w_kernel<<<(n_wel + 255)/256, 256, 0, stream>>>(W, (float*)Wp4, n_wel);
        scatter_bins_kernel<<<(n_edges + 255)/256, 256, 0, stream>>>(nbr, cnt, bins, n_edges);
        accum_gather_kernel<<<(n_atoms + 63)/64, 256, 0, stream>>>(
            RZ, Wp4, cnt, bins, out, n_atoms);
    }
}